// Round 2
// baseline (877.252 us; speedup 1.0000x reference)
//
#include <hip/hip_runtime.h>
#include <stdint.h>

constexpr int Bn = 8, Nn = 4096, Sn = 1024, Cc = 64, KNN = 32, C1 = 128, C2 = 256;
constexpr int Qq = Bn * Sn;     // 8192 queries
constexpr int Mm = Qq * KNN;    // 262144 samples
constexpr int OUT_XYZ = Bn * Sn * 3;  // 24576 floats (output 0)
constexpr float BNEPS = 1e-5f;

// ---------- ws layout ----------
constexpr size_t SZ_IDX  = (size_t)Qq * KNN * 4;        // 1 MB
constexpr size_t SZ_PTST = (size_t)Bn * Nn * Cc * 4;    // 8 MB
constexpr int    NB_MLP  = Mm / 64;                     // 4096 blocks
constexpr size_t SZ_PART = (size_t)NB_MLP * 512 * 4;    // 8 MB
constexpr size_t SZ_PB   = (size_t)128 * 512 * 4;       // 256 KB
constexpr size_t OFF_IDX  = 0;
constexpr size_t OFF_PTST = OFF_IDX + SZ_IDX;
constexpr size_t OFF_P1   = OFF_PTST + SZ_PTST;
constexpr size_t OFF_P2   = OFF_P1 + SZ_PART;
constexpr size_t OFF_P1B  = OFF_P2 + SZ_PART;
constexpr size_t OFF_P2B  = OFF_P1B + SZ_PB;
constexpr size_t OFF_BN1  = OFF_P2B + SZ_PB;
constexpr size_t OFF_BN2  = OFF_BN1 + 1024;
constexpr size_t OFF_W2T  = OFF_BN2 + 2048;
constexpr size_t OFF_Y1   = (OFF_W2T + (size_t)C1 * C2 * 4 + 255) & ~(size_t)255;
constexpr size_t OFF_Y2   = OFF_Y1 + (size_t)Mm * C1 * 2;   // y1 bf16
constexpr size_t NEED_B   = OFF_Y2;                          // ~90 MB
constexpr size_t NEED_A   = OFF_Y2 + (size_t)Mm * C2 * 2;    // ~218 MB

__device__ __forceinline__ unsigned short f2bf(float f) {
  unsigned u = __float_as_uint(f);
  u = u + 0x7FFFu + ((u >> 16) & 1u);   // RNE
  return (unsigned short)(u >> 16);
}
__device__ __forceinline__ float bf2f(unsigned short h) {
  return __uint_as_float(((unsigned)h) << 16);
}

// ---------- trivial copy of new_xyz to output 0 ----------
__global__ __launch_bounds__(256) void k_copy_nxyz(const float* __restrict__ src,
                                                   float* __restrict__ dst) {
  int i = threadIdx.x + blockIdx.x * 256;
  if (i < OUT_XYZ) dst[i] = src[i];
}

// ---------- points [B,C,N] -> ptsT [B,N,C] ----------
__global__ __launch_bounds__(256) void k_ptsT(const float* __restrict__ pts,
                                              float* __restrict__ ptsT) {
  __shared__ float tile[64][65];
  int b = blockIdx.y, n0 = blockIdx.x * 64;
  int cl = threadIdx.x & 63, rw = threadIdx.x >> 6;
#pragma unroll
  for (int i = 0; i < 16; ++i) {
    int c = i * 4 + rw;
    tile[cl][c] = pts[((size_t)b * Cc + c) * Nn + n0 + cl];
  }
  __syncthreads();
#pragma unroll
  for (int i = 0; i < 16; ++i) {
    int nf = i * 4 + rw;
    ptsT[((size_t)b * Nn + n0 + nf) * Cc + cl] = tile[nf][cl];
  }
}

// ---------- W2 [256,128] -> W2T [128,256] ----------
__global__ __launch_bounds__(256) void k_w2t(const float* __restrict__ W2,
                                             float* __restrict__ W2T) {
  for (int u = threadIdx.x + blockIdx.x * 256; u < C2 * C1; u += 256 * 64) {
    int r = u >> 7, c = u & 127;
    W2T[c * C2 + r] = W2[u];
  }
}

// ---------- kNN: one block (256 thr) per query, cached tournament ----------
// Distance arithmetic replicates the reference evaluation bitwise:
//   norms: mul then sequential adds (no FMA):  (x*x + y*y) + z*z
//   dot:   gemm-style FMA chain:               fma(z,z', fma(y,y', rn(x*x')))
//   combine: (sqq + sqp) - 2*dot
__global__ __launch_bounds__(256) void k_knn(const float* __restrict__ xyz,
                                             const float* __restrict__ nxyz,
                                             int* __restrict__ idxout) {
  int q = blockIdx.x;
  int b = q >> 10;
  int t = threadIdx.x;
  const float* xb = xyz + (size_t)b * Nn * 3;
  float qx = nxyz[q * 3 + 0], qy = nxyz[q * 3 + 1], qz = nxyz[q * 3 + 2];
  float sqq = __fadd_rn(__fadd_rn(__fmul_rn(qx, qx), __fmul_rn(qy, qy)), __fmul_rn(qz, qz));
  float d[16];
#pragma unroll
  for (int i = 0; i < 16; ++i) {
    int p = t + (i << 8);
    float xl = xb[p * 3 + 0], yl = xb[p * 3 + 1], zl = xb[p * 3 + 2];
    float sqp = __fadd_rn(__fadd_rn(__fmul_rn(xl, xl), __fmul_rn(yl, yl)), __fmul_rn(zl, zl));
    float dot = __fmaf_rn(qz, zl, __fmaf_rn(qy, yl, __fmul_rn(qx, xl)));
    d[i] = __fsub_rn(__fadd_rn(sqq, sqp), __fmul_rn(2.0f, dot));
  }
  float lv = d[0]; int li = t;
#pragma unroll
  for (int i = 1; i < 16; ++i) {
    int p = t + (i << 8);
    if (d[i] < lv) { lv = d[i]; li = p; }
  }
  __shared__ float wmin[4];
  __shared__ int widx[4];
  for (int r = 0; r < KNN; ++r) {
    float v = lv; int ii = li;
#pragma unroll
    for (int off = 32; off >= 1; off >>= 1) {
      float ov = __shfl_xor(v, off);
      int oi = __shfl_xor(ii, off);
      if (ov < v || (ov == v && oi < ii)) { v = ov; ii = oi; }
    }
    if ((t & 63) == 0) { wmin[t >> 6] = v; widx[t >> 6] = ii; }
    __syncthreads();
    float bv = wmin[0]; int bi = widx[0];
#pragma unroll
    for (int w = 1; w < 4; ++w) {
      float ov = wmin[w]; int oi = widx[w];
      if (ov < bv || (ov == bv && oi < bi)) { bv = ov; bi = oi; }
    }
    if (t == 0) idxout[q * KNN + r] = bi;
    if ((bi & 255) == t) {              // owner eliminates + rescans
      int j = bi >> 8;
#pragma unroll
      for (int i = 0; i < 16; ++i)
        if (i == j) d[i] = 3.0e38f;
      lv = d[0]; li = t;
#pragma unroll
      for (int i = 1; i < 16; ++i) {
        int p = t + (i << 8);
        if (d[i] < lv) { lv = d[i]; li = p; }
      }
    }
    __syncthreads();
  }
}

// ---------- layer1: gather + W1 matvec + bias; write y1 bf16; stats partials ----------
__global__ __launch_bounds__(256) void k_mlp1(const float* __restrict__ W1g,
                                              const float* __restrict__ b1,
                                              const float* __restrict__ ptsT,
                                              const float* __restrict__ xyz,
                                              const float* __restrict__ nxyz,
                                              const int* __restrict__ idx,
                                              unsigned short* __restrict__ y1,
                                              float* __restrict__ part1) {
  __shared__ float w1s[C1 * 72];   // [128][72], cols 70..71 zero
  __shared__ float gs[64 * 72];    // [64 samples][72]
  int t = threadIdx.x;
  int m0 = blockIdx.x * 64;
  int b = m0 >> 15;                // S*K = 32768 samples per batch
  for (int u = t; u < C1 * 72; u += 256) {
    int ch = u / 72, c = u - ch * 72;
    w1s[u] = (c < 70) ? W1g[ch * 70 + c] : 0.0f;
  }
  {
    int j = t & 63, quarter = t >> 6;
    int m = m0 + j;
    int pid = idx[m];
    const float* src = ptsT + ((size_t)b * Nn + pid) * Cc + quarter * 16;
    float* dst = gs + j * 72 + quarter * 16;
#pragma unroll
    for (int u = 0; u < 16; u += 4)
      *reinterpret_cast<float4*>(dst + u) = *reinterpret_cast<const float4*>(src + u);
    if (quarter == 0) {
      int s = (m >> 5) & (Sn - 1);
      const float* xp = xyz + ((size_t)b * Nn + pid) * 3;
      gs[j * 72 + 64] = xp[0]; gs[j * 72 + 65] = xp[1]; gs[j * 72 + 66] = xp[2];
      const float* qp = nxyz + ((size_t)(b * Sn + s)) * 3;
      gs[j * 72 + 67] = qp[0]; gs[j * 72 + 68] = qp[1]; gs[j * 72 + 69] = qp[2];
      gs[j * 72 + 70] = 0.0f; gs[j * 72 + 71] = 0.0f;
    }
  }
  __syncthreads();
  int ch = t & 127, h = t >> 7;
  float acc[32];
  float bv = b1[ch];
#pragma unroll
  for (int j = 0; j < 32; ++j) acc[j] = bv;
  const float* gbase = gs + (h * 32) * 72;
  for (int c0 = 0; c0 < 72; c0 += 4) {
    float4 wv = *reinterpret_cast<const float4*>(w1s + ch * 72 + c0);
#pragma unroll
    for (int j = 0; j < 32; ++j) {
      float4 gv = *reinterpret_cast<const float4*>(gbase + j * 72 + c0);
      acc[j] += wv.x * gv.x + wv.y * gv.y + wv.z * gv.z + wv.w * gv.w;
    }
  }
  float sum = 0.f, ss = 0.f;
#pragma unroll
  for (int j = 0; j < 32; ++j) {
    float v = acc[j];
    sum += v; ss += v * v;
    y1[(size_t)(m0 + h * 32 + j) * C1 + ch] = f2bf(v);
  }
  float* p = part1 + (size_t)blockIdx.x * 512;
  p[h * 128 + ch] = sum;
  p[256 + h * 128 + ch] = ss;
}

// ---------- stats reduce (layer1) ----------
__global__ __launch_bounds__(256) void k_red1a(const float* __restrict__ part1,
                                               float* __restrict__ p1b) {
  int t = threadIdx.x, r = blockIdx.x;       // 128 blocks x 32 rows
  int ch = t & 127, which = t >> 7;
  float acc = 0.f;
  for (int row = r * 32; row < r * 32 + 32; ++row) {
    const float* p = part1 + (size_t)row * 512 + which * 256;
    acc += p[ch] + p[128 + ch];
  }
  p1b[r * 256 + which * 128 + ch] = acc;
}
__global__ __launch_bounds__(256) void k_red1b(const float* __restrict__ p1b,
                                               const float* __restrict__ g1,
                                               const float* __restrict__ be1,
                                               float* __restrict__ bn1) {
  __shared__ float lds[256];
  int t = threadIdx.x;
  float acc = 0.f;
  for (int row = 0; row < 128; ++row) acc += p1b[row * 256 + t];
  lds[t] = acc;
  __syncthreads();
  if (t < 128) {
    float sum = lds[t], ss = lds[128 + t];
    float mean = sum / (float)Mm;
    float var = ss / (float)Mm - mean * mean;
    float a = g1[t] * rsqrtf(var + BNEPS);
    bn1[t] = a;
    bn1[128 + t] = be1[t] - mean * a;
  }
}

// ---------- layer2: z1=BNrelu(y1); y2=W2 z1 + b2; stats partials; opt write y2 ----------
template <int WRITE_Y2>
__global__ __launch_bounds__(256) void k_mlp2(const unsigned short* __restrict__ y1,
                                              const float* __restrict__ bn1,
                                              const float* __restrict__ W2T,
                                              const float* __restrict__ b2,
                                              unsigned short* __restrict__ y2,
                                              float* __restrict__ part2) {
  __shared__ float zs[64 * 132];
  __shared__ float bns[256];
  int t = threadIdx.x;
  int m0 = blockIdx.x * 64;
  bns[t] = bn1[t];
  __syncthreads();
  {
    int j = t >> 2, cq = (t & 3) * 32;
    const unsigned short* src = y1 + (size_t)(m0 + j) * C1 + cq;
    float* dst = zs + j * 132 + cq;
#pragma unroll
    for (int u = 0; u < 32; u += 8) {
      uint4 v = *reinterpret_cast<const uint4*>(src + u);
      unsigned arr[4] = {v.x, v.y, v.z, v.w};
#pragma unroll
      for (int e = 0; e < 4; ++e) {
        int c = cq + u + e * 2;
        float lo = __uint_as_float(arr[e] << 16);
        float hi = __uint_as_float(arr[e] & 0xFFFF0000u);
        dst[u + e * 2]     = fmaxf(0.f, bns[c] * lo + bns[128 + c]);
        dst[u + e * 2 + 1] = fmaxf(0.f, bns[c + 1] * hi + bns[128 + c + 1]);
      }
    }
  }
  __syncthreads();
  float acc[64];
  float bv = b2[t];
#pragma unroll
  for (int j = 0; j < 64; ++j) acc[j] = bv;
  for (int c0 = 0; c0 < C1; c0 += 4) {
    float w0 = W2T[(c0 + 0) * C2 + t];
    float w1 = W2T[(c0 + 1) * C2 + t];
    float w2 = W2T[(c0 + 2) * C2 + t];
    float w3 = W2T[(c0 + 3) * C2 + t];
#pragma unroll
    for (int j = 0; j < 64; ++j) {
      float4 zv = *reinterpret_cast<const float4*>(zs + j * 132 + c0);
      acc[j] += w0 * zv.x + w1 * zv.y + w2 * zv.z + w3 * zv.w;
    }
  }
  float sum = 0.f, ss = 0.f;
#pragma unroll
  for (int j = 0; j < 64; ++j) {
    float v = acc[j];
    sum += v; ss += v * v;
    if (WRITE_Y2) y2[(size_t)(m0 + j) * C2 + t] = f2bf(v);
  }
  part2[(size_t)blockIdx.x * 512 + t] = sum;
  part2[(size_t)blockIdx.x * 512 + 256 + t] = ss;
}

// ---------- stats reduce (layer2) ----------
__global__ __launch_bounds__(512) void k_red2a(const float* __restrict__ part2,
                                               float* __restrict__ p2b) {
  int t = threadIdx.x, r = blockIdx.x;       // 128 blocks x 32 rows
  float acc = 0.f;
  for (int row = r * 32; row < r * 32 + 32; ++row)
    acc += part2[(size_t)row * 512 + t];
  p2b[r * 512 + t] = acc;
}
__global__ __launch_bounds__(512) void k_red2b(const float* __restrict__ p2b,
                                               const float* __restrict__ g2,
                                               const float* __restrict__ be2,
                                               float* __restrict__ bn2) {
  __shared__ float lds[512];
  int t = threadIdx.x;
  float acc = 0.f;
  for (int row = 0; row < 128; ++row) acc += p2b[row * 512 + t];
  lds[t] = acc;
  __syncthreads();
  if (t < 256) {
    float sum = lds[t], ss = lds[256 + t];
    float mean = sum / (float)Mm;
    float var = ss / (float)Mm - mean * mean;
    float a = g2[t] * rsqrtf(var + BNEPS);
    bn2[t] = a;
    bn2[256 + t] = be2[t] - mean * a;
  }
}

// ---------- epilogue tier A: read y2 bf16, BN+relu, max over k, transposed store ----------
__global__ __launch_bounds__(256) void k_out_a(const unsigned short* __restrict__ y2,
                                               const float* __restrict__ bn2,
                                               float* __restrict__ out) {
  __shared__ float tile[64][65];
  int b = blockIdx.z, ch0 = blockIdx.y * 64, s0 = blockIdx.x * 64;
  int t = threadIdx.x;
  int chl = t & 63, sr = t >> 6;
  float a = bn2[ch0 + chl], cc = bn2[256 + ch0 + chl];
#pragma unroll
  for (int i = 0; i < 16; ++i) {
    int sl = sr * 16 + i;
    int q = b * Sn + s0 + sl;
    const unsigned short* row = y2 + (size_t)q * KNN * C2 + ch0 + chl;
    float m = -3.0e38f;
#pragma unroll 4
    for (int k = 0; k < KNN; ++k) {
      float v = bf2f(row[(size_t)k * C2]);
      m = fmaxf(m, a * v + cc);
    }
    tile[chl][sl] = fmaxf(0.f, m);
  }
  __syncthreads();
  int sl = t & 63, cr = t >> 6;
#pragma unroll
  for (int i = 0; i < 16; ++i) {
    int chl2 = i * 4 + cr;
    out[OUT_XYZ + ((size_t)(b * C2 + ch0 + chl2)) * Sn + s0 + sl] = tile[chl2][sl];
  }
}

// ---------- epilogue tier B: recompute y2 from y1, BN+relu, max over k ----------
__global__ __launch_bounds__(256) void k_out_b(const unsigned short* __restrict__ y1,
                                               const float* __restrict__ bn1,
                                               const float* __restrict__ W2T,
                                               const float* __restrict__ b2,
                                               const float* __restrict__ bn2,
                                               float* __restrict__ out) {
  __shared__ float zs[32 * 132];
  __shared__ float bns[256];
  int t = threadIdx.x;
  int q = blockIdx.x;
  int m0 = q * KNN;
  bns[t] = bn1[t];
  __syncthreads();
  {
    int j = t >> 3, co = (t & 7) * 16;
    const unsigned short* src = y1 + (size_t)(m0 + j) * C1 + co;
    float* dst = zs + j * 132 + co;
#pragma unroll
    for (int u = 0; u < 16; u += 8) {
      uint4 v = *reinterpret_cast<const uint4*>(src + u);
      unsigned arr[4] = {v.x, v.y, v.z, v.w};
#pragma unroll
      for (int e = 0; e < 4; ++e) {
        int c = co + u + e * 2;
        float lo = __uint_as_float(arr[e] << 16);
        float hi = __uint_as_float(arr[e] & 0xFFFF0000u);
        dst[u + e * 2]     = fmaxf(0.f, bns[c] * lo + bns[128 + c]);
        dst[u + e * 2 + 1] = fmaxf(0.f, bns[c + 1] * hi + bns[128 + c + 1]);
      }
    }
  }
  __syncthreads();
  float acc[32];
  float bv = b2[t];
#pragma unroll
  for (int j = 0; j < 32; ++j) acc[j] = bv;
  for (int c0 = 0; c0 < C1; c0 += 4) {
    float w0 = W2T[(c0 + 0) * C2 + t];
    float w1 = W2T[(c0 + 1) * C2 + t];
    float w2 = W2T[(c0 + 2) * C2 + t];
    float w3 = W2T[(c0 + 3) * C2 + t];
#pragma unroll
    for (int j = 0; j < 32; ++j) {
      float4 zv = *reinterpret_cast<const float4*>(zs + j * 132 + c0);
      acc[j] += w0 * zv.x + w1 * zv.y + w2 * zv.z + w3 * zv.w;
    }
  }
  float a = bn2[t], cc = bn2[256 + t];
  float m = -3.0e38f;
#pragma unroll
  for (int j = 0; j < 32; ++j) m = fmaxf(m, a * acc[j] + cc);
  int b = q >> 10, s = q & (Sn - 1);
  out[OUT_XYZ + ((size_t)(b * C2 + t)) * Sn + s] = fmaxf(0.f, m);
}

extern "C" void kernel_launch(void* const* d_in, const int* in_sizes, int n_in,
                              void* d_out, int out_size, void* d_ws, size_t ws_size,
                              hipStream_t stream) {
  (void)in_sizes; (void)n_in; (void)out_size;
  const float* xyz  = (const float*)d_in[0];
  const float* pts  = (const float*)d_in[1];
  const float* nxyz = (const float*)d_in[2];
  const float* W1   = (const float*)d_in[3];
  const float* b1   = (const float*)d_in[4];
  const float* g1   = (const float*)d_in[5];
  const float* be1  = (const float*)d_in[6];
  const float* W2   = (const float*)d_in[7];
  const float* b2   = (const float*)d_in[8];
  const float* g2   = (const float*)d_in[9];
  const float* be2  = (const float*)d_in[10];
  float* out = (float*)d_out;
  char* ws = (char*)d_ws;

  int*            idx   = (int*)(ws + OFF_IDX);
  float*          ptsT  = (float*)(ws + OFF_PTST);
  float*          part1 = (float*)(ws + OFF_P1);
  float*          part2 = (float*)(ws + OFF_P2);
  float*          p1b   = (float*)(ws + OFF_P1B);
  float*          p2b   = (float*)(ws + OFF_P2B);
  float*          bn1   = (float*)(ws + OFF_BN1);
  float*          bn2   = (float*)(ws + OFF_BN2);
  float*          W2T   = (float*)(ws + OFF_W2T);
  unsigned short* y1    = (unsigned short*)(ws + OFF_Y1);
  unsigned short* y2    = (unsigned short*)(ws + OFF_Y2);

  const bool tierA = ws_size >= NEED_A;

  k_copy_nxyz<<<(OUT_XYZ + 255) / 256, 256, 0, stream>>>(nxyz, out);
  k_ptsT<<<dim3(Nn / 64, Bn), 256, 0, stream>>>(pts, ptsT);
  k_w2t<<<64, 256, 0, stream>>>(W2, W2T);
  k_knn<<<Qq, 256, 0, stream>>>(xyz, nxyz, idx);
  k_mlp1<<<NB_MLP, 256, 0, stream>>>(W1, b1, ptsT, xyz, nxyz, idx, y1, part1);
  k_red1a<<<128, 256, 0, stream>>>(part1, p1b);
  k_red1b<<<1, 256, 0, stream>>>(p1b, g1, be1, bn1);
  if (tierA)
    k_mlp2<1><<<NB_MLP, 256, 0, stream>>>(y1, bn1, W2T, b2, y2, part2);
  else
    k_mlp2<0><<<NB_MLP, 256, 0, stream>>>(y1, bn1, W2T, b2, y2, part2);
  k_red2a<<<128, 512, 0, stream>>>(part2, p2b);
  k_red2b<<<1, 512, 0, stream>>>(p2b, g2, be2, bn2);
  if (tierA)
    k_out_a<<<dim3(Sn / 64, C2 / 64, Bn), 256, 0, stream>>>(y2, bn2, out);
  else
    k_out_b<<<Qq, 256, 0, stream>>>(y1, bn1, W2T, b2, bn2, out);
}

// Round 3
// 511.147 us; speedup vs baseline: 1.7162x; 1.7162x over previous
//
#include <hip/hip_runtime.h>
#include <stdint.h>

constexpr int Bn = 8, Nn = 4096, Sn = 1024, Cc = 64, KNN = 32, C1 = 128, C2 = 256;
constexpr int Qq = Bn * Sn;     // 8192 queries
constexpr int Mm = Qq * KNN;    // 262144 samples
constexpr int OUT_XYZ = Bn * Sn * 3;  // 24576 floats (output 0)
constexpr float BNEPS = 1e-5f;

// ---------- ws layout ----------
constexpr size_t SZ_IDX  = (size_t)Qq * KNN * 4;        // 1 MB
constexpr size_t SZ_PTST = (size_t)Bn * Nn * Cc * 4;    // 8 MB
constexpr int    NB_MLP  = Mm / 64;                     // 4096 blocks
constexpr size_t SZ_PART = (size_t)NB_MLP * 512 * 4;    // 8 MB
constexpr size_t SZ_PB   = (size_t)128 * 512 * 4;       // 256 KB
constexpr size_t OFF_IDX  = 0;
constexpr size_t OFF_PTST = OFF_IDX + SZ_IDX;
constexpr size_t OFF_P1   = OFF_PTST + SZ_PTST;
constexpr size_t OFF_P2   = OFF_P1 + SZ_PART;
constexpr size_t OFF_P1B  = OFF_P2 + SZ_PART;
constexpr size_t OFF_P2B  = OFF_P1B + SZ_PB;
constexpr size_t OFF_BN1  = OFF_P2B + SZ_PB;
constexpr size_t OFF_BN2  = OFF_BN1 + 1024;
constexpr size_t OFF_W2F  = OFF_BN2 + 2048;              // 64 KB bf16 frag-packed W2
constexpr size_t OFF_Y1   = (OFF_W2F + (size_t)C1 * C2 * 2 + 255) & ~(size_t)255;
// total ws need ≈ OFF_Y1 + 67 MB

typedef __attribute__((ext_vector_type(8))) __bf16 bf16x8;
typedef __attribute__((ext_vector_type(4))) float f32x4;

__device__ __forceinline__ unsigned short f2bf(float f) {
  unsigned u = __float_as_uint(f);
  u = u + 0x7FFFu + ((u >> 16) & 1u);   // RNE
  return (unsigned short)(u >> 16);
}
__device__ __forceinline__ float bf2f(unsigned short h) {
  return __uint_as_float(((unsigned)h) << 16);
}

// ---------- trivial copy of new_xyz to output 0 ----------
__global__ __launch_bounds__(256) void k_copy_nxyz(const float* __restrict__ src,
                                                   float* __restrict__ dst) {
  int i = threadIdx.x + blockIdx.x * 256;
  if (i < OUT_XYZ) dst[i] = src[i];
}

// ---------- points [B,C,N] -> ptsT [B,N,C] ----------
__global__ __launch_bounds__(256) void k_ptsT(const float* __restrict__ pts,
                                              float* __restrict__ ptsT) {
  __shared__ float tile[64][65];
  int b = blockIdx.y, n0 = blockIdx.x * 64;
  int cl = threadIdx.x & 63, rw = threadIdx.x >> 6;
#pragma unroll
  for (int i = 0; i < 16; ++i) {
    int c = i * 4 + rw;
    tile[cl][c] = pts[((size_t)b * Cc + c) * Nn + n0 + cl];
  }
  __syncthreads();
#pragma unroll
  for (int i = 0; i < 16; ++i) {
    int nf = i * 4 + rw;
    ptsT[((size_t)b * Nn + n0 + nf) * Cc + cl] = tile[nf][cl];
  }
}

// ---------- W2 [256,128] f32 -> bf16 MFMA B-fragment order ----------
// frag layout: w2f[((ntile*4+ks)*64 + lane)*8 + j] = W2[ntile*16+(lane&15)][ks*32+(lane>>4)*8+j]
__global__ __launch_bounds__(256) void k_w2f(const float* __restrict__ W2,
                                             unsigned short* __restrict__ w2f) {
  int u = threadIdx.x + blockIdx.x * 256;   // 32768 total
  int j = u & 7, lane = (u >> 3) & 63, ks = (u >> 9) & 3, ntile = u >> 11;
  int col = ntile * 16 + (lane & 15);
  int k = ks * 32 + (lane >> 4) * 8 + j;
  w2f[u] = f2bf(W2[col * C1 + k]);
}

// ---------- kNN: one block (256 thr) per query, cached tournament ----------
__global__ __launch_bounds__(256) void k_knn(const float* __restrict__ xyz,
                                             const float* __restrict__ nxyz,
                                             int* __restrict__ idxout) {
  int q = blockIdx.x;
  int b = q >> 10;
  int t = threadIdx.x;
  const float* xb = xyz + (size_t)b * Nn * 3;
  float qx = nxyz[q * 3 + 0], qy = nxyz[q * 3 + 1], qz = nxyz[q * 3 + 2];
  float sqq = __fadd_rn(__fadd_rn(__fmul_rn(qx, qx), __fmul_rn(qy, qy)), __fmul_rn(qz, qz));
  float d[16];
#pragma unroll
  for (int i = 0; i < 16; ++i) {
    int p = t + (i << 8);
    float xl = xb[p * 3 + 0], yl = xb[p * 3 + 1], zl = xb[p * 3 + 2];
    float sqp = __fadd_rn(__fadd_rn(__fmul_rn(xl, xl), __fmul_rn(yl, yl)), __fmul_rn(zl, zl));
    float dot = __fmaf_rn(qz, zl, __fmaf_rn(qy, yl, __fmul_rn(qx, xl)));
    d[i] = __fsub_rn(__fadd_rn(sqq, sqp), __fmul_rn(2.0f, dot));
  }
  float lv = d[0]; int li = t;
#pragma unroll
  for (int i = 1; i < 16; ++i) {
    int p = t + (i << 8);
    if (d[i] < lv) { lv = d[i]; li = p; }
  }
  __shared__ float wmin[4];
  __shared__ int widx[4];
  for (int r = 0; r < KNN; ++r) {
    float v = lv; int ii = li;
#pragma unroll
    for (int off = 32; off >= 1; off >>= 1) {
      float ov = __shfl_xor(v, off);
      int oi = __shfl_xor(ii, off);
      if (ov < v || (ov == v && oi < ii)) { v = ov; ii = oi; }
    }
    if ((t & 63) == 0) { wmin[t >> 6] = v; widx[t >> 6] = ii; }
    __syncthreads();
    float bv = wmin[0]; int bi = widx[0];
#pragma unroll
    for (int w = 1; w < 4; ++w) {
      float ov = wmin[w]; int oi = widx[w];
      if (ov < bv || (ov == bv && oi < bi)) { bv = ov; bi = oi; }
    }
    if (t == 0) idxout[q * KNN + r] = bi;
    if ((bi & 255) == t) {              // owner eliminates + rescans
      int j = bi >> 8;
#pragma unroll
      for (int i = 0; i < 16; ++i)
        if (i == j) d[i] = 3.0e38f;
      lv = d[0]; li = t;
#pragma unroll
      for (int i = 1; i < 16; ++i) {
        int p = t + (i << 8);
        if (d[i] < lv) { lv = d[i]; li = p; }
      }
    }
    __syncthreads();
  }
}

// ---------- layer1: gather + W1 matvec + bias; write y1 bf16; stats partials ----------
__global__ __launch_bounds__(256) void k_mlp1(const float* __restrict__ W1g,
                                              const float* __restrict__ b1,
                                              const float* __restrict__ ptsT,
                                              const float* __restrict__ xyz,
                                              const float* __restrict__ nxyz,
                                              const int* __restrict__ idx,
                                              unsigned short* __restrict__ y1,
                                              float* __restrict__ part1) {
  __shared__ float w1s[C1 * 72];   // [128][72], cols 70..71 zero
  __shared__ float gs[64 * 72];    // [64 samples][72]
  int t = threadIdx.x;
  int m0 = blockIdx.x * 64;
  int b = m0 >> 15;                // S*K = 32768 samples per batch
  for (int u = t; u < C1 * 72; u += 256) {
    int ch = u / 72, c = u - ch * 72;
    w1s[u] = (c < 70) ? W1g[ch * 70 + c] : 0.0f;
  }
  {
    int j = t & 63, quarter = t >> 6;
    int m = m0 + j;
    int pid = idx[m];
    const float* src = ptsT + ((size_t)b * Nn + pid) * Cc + quarter * 16;
    float* dst = gs + j * 72 + quarter * 16;
#pragma unroll
    for (int u = 0; u < 16; u += 4)
      *reinterpret_cast<float4*>(dst + u) = *reinterpret_cast<const float4*>(src + u);
    if (quarter == 0) {
      int s = (m >> 5) & (Sn - 1);
      const float* xp = xyz + ((size_t)b * Nn + pid) * 3;
      gs[j * 72 + 64] = xp[0]; gs[j * 72 + 65] = xp[1]; gs[j * 72 + 66] = xp[2];
      const float* qp = nxyz + ((size_t)(b * Sn + s)) * 3;
      gs[j * 72 + 67] = qp[0]; gs[j * 72 + 68] = qp[1]; gs[j * 72 + 69] = qp[2];
      gs[j * 72 + 70] = 0.0f; gs[j * 72 + 71] = 0.0f;
    }
  }
  __syncthreads();
  int ch = t & 127, h = t >> 7;
  float acc[32];
  float bv = b1[ch];
#pragma unroll
  for (int j = 0; j < 32; ++j) acc[j] = bv;
  const float* gbase = gs + (h * 32) * 72;
  for (int c0 = 0; c0 < 72; c0 += 4) {
    float4 wv = *reinterpret_cast<const float4*>(w1s + ch * 72 + c0);
#pragma unroll
    for (int j = 0; j < 32; ++j) {
      float4 gv = *reinterpret_cast<const float4*>(gbase + j * 72 + c0);
      acc[j] += wv.x * gv.x + wv.y * gv.y + wv.z * gv.z + wv.w * gv.w;
    }
  }
  float sum = 0.f, ss = 0.f;
#pragma unroll
  for (int j = 0; j < 32; ++j) {
    float v = acc[j];
    sum += v; ss += v * v;
    y1[(size_t)(m0 + h * 32 + j) * C1 + ch] = f2bf(v);
  }
  float* p = part1 + (size_t)blockIdx.x * 512;
  p[h * 128 + ch] = sum;
  p[256 + h * 128 + ch] = ss;
}

// ---------- stats reduce (layer1) ----------
__global__ __launch_bounds__(256) void k_red1a(const float* __restrict__ part1,
                                               float* __restrict__ p1b) {
  int t = threadIdx.x, r = blockIdx.x;       // 128 blocks x 32 rows
  int ch = t & 127, which = t >> 7;
  float acc = 0.f;
  for (int row = r * 32; row < r * 32 + 32; ++row) {
    const float* p = part1 + (size_t)row * 512 + which * 256;
    acc += p[ch] + p[128 + ch];
  }
  p1b[r * 256 + which * 128 + ch] = acc;
}
__global__ __launch_bounds__(256) void k_red1b(const float* __restrict__ p1b,
                                               const float* __restrict__ g1,
                                               const float* __restrict__ be1,
                                               float* __restrict__ bn1) {
  __shared__ float lds[256];
  int t = threadIdx.x;
  float acc = 0.f;
  for (int row = 0; row < 128; ++row) acc += p1b[row * 256 + t];
  lds[t] = acc;
  __syncthreads();
  if (t < 128) {
    float sum = lds[t], ss = lds[128 + t];
    float mean = sum / (float)Mm;
    float var = ss / (float)Mm - mean * mean;
    float a = g1[t] * rsqrtf(var + BNEPS);
    bn1[t] = a;
    bn1[128 + t] = be1[t] - mean * a;
  }
}

// ---------- layer2 MFMA: z1=BNrelu(y1) bf16 -> y2 = W2 z1 + b2 (in acc) ----------
// OUTP=0: per-channel sum/sumsq partials of y2 into part2 (no y2 store).
// OUTP=1: recompute y2, fuse BN2+relu+max-over-k, store out[B,C2,S] directly.
template <int OUTP>
__global__ __launch_bounds__(256) void k_m2(const unsigned short* __restrict__ y1,
                                            const float* __restrict__ bn1c,
                                            const unsigned short* __restrict__ w2f,
                                            const float* __restrict__ b2,
                                            float* __restrict__ part2,
                                            const float* __restrict__ bn2c,
                                            float* __restrict__ out) {
  __shared__ unsigned short zs[64 * 128];   // XOR-swizzled, byte ^= (row&7)<<4
  __shared__ float bns[256];
  int t = threadIdx.x;
  int m0 = blockIdx.x * 64;
  bns[t] = bn1c[t];
  // y1 tile load (coalesced 16B/lane)
  uint4 yv[4];
  const uint4* ybase = reinterpret_cast<const uint4*>(y1 + (size_t)m0 * C1);
#pragma unroll
  for (int i = 0; i < 4; ++i) yv[i] = ybase[t + i * 256];
  // W2 B-fragments for this wave's 64 output cols (L2-hot)
  int lane = t & 63, w = t >> 6;
  bf16x8 bfrag[4][4];
  {
    const uint4* wp = reinterpret_cast<const uint4*>(w2f) + (size_t)(w * 4) * 4 * 64 + lane;
#pragma unroll
    for (int nt = 0; nt < 4; ++nt)
#pragma unroll
      for (int ks = 0; ks < 4; ++ks)
        bfrag[nt][ks] = __builtin_bit_cast(bf16x8, wp[(nt * 4 + ks) * 64]);
  }
  __syncthreads();   // bns ready
  // BN1+relu -> bf16 -> swizzled LDS
#pragma unroll
  for (int i = 0; i < 4; ++i) {
    int chunk = t + i * 256;
    int row = chunk >> 4, kc = chunk & 15;
    unsigned arr[4] = {yv[i].x, yv[i].y, yv[i].z, yv[i].w};
    unsigned zo[4];
#pragma unroll
    for (int e = 0; e < 4; ++e) {
      int c = kc * 8 + e * 2;
      float lo = __uint_as_float(arr[e] << 16);
      float hi = __uint_as_float(arr[e] & 0xFFFF0000u);
      float z0 = fmaxf(0.f, bns[c] * lo + bns[128 + c]);
      float z1 = fmaxf(0.f, bns[c + 1] * hi + bns[128 + c + 1]);
      zo[e] = (unsigned)f2bf(z0) | ((unsigned)f2bf(z1) << 16);
    }
    int byte = (row * 256 + kc * 16) ^ ((row & 7) << 4);
    *reinterpret_cast<uint4*>(reinterpret_cast<char*>(zs) + byte) =
        make_uint4(zo[0], zo[1], zo[2], zo[3]);
  }
  __syncthreads();
  // MFMA: 64 rows x (this wave's 64 cols), K=128
  f32x4 acc[4][4];
#pragma unroll
  for (int mt = 0; mt < 4; ++mt)
#pragma unroll
    for (int nt = 0; nt < 4; ++nt) acc[mt][nt] = f32x4{0.f, 0.f, 0.f, 0.f};
  int r15 = lane & 15, rhi = lane >> 4;
#pragma unroll
  for (int mt = 0; mt < 4; ++mt) {
    int row = mt * 16 + r15;
    bf16x8 af[4];
#pragma unroll
    for (int ks = 0; ks < 4; ++ks) {
      int byte = (row * 256 + ks * 64 + rhi * 16) ^ ((row & 7) << 4);
      af[ks] = __builtin_bit_cast(
          bf16x8, *reinterpret_cast<const uint4*>(reinterpret_cast<const char*>(zs) + byte));
    }
#pragma unroll
    for (int nt = 0; nt < 4; ++nt)
#pragma unroll
      for (int ks = 0; ks < 4; ++ks)
        acc[mt][nt] =
            __builtin_amdgcn_mfma_f32_16x16x32_bf16(af[ks], bfrag[nt][ks], acc[mt][nt], 0, 0, 0);
  }
  int wn0 = w * 64;
  if (OUTP == 0) {
#pragma unroll
    for (int nt = 0; nt < 4; ++nt) {
      int col = wn0 + nt * 16 + r15;
      float bv = b2[col];
      float s = 0.f, ss = 0.f;
#pragma unroll
      for (int mt = 0; mt < 4; ++mt)
#pragma unroll
        for (int rg = 0; rg < 4; ++rg) {
          float v = acc[mt][nt][rg] + bv;
          s += v; ss += v * v;
        }
      s += __shfl_xor(s, 16); s += __shfl_xor(s, 32);
      ss += __shfl_xor(ss, 16); ss += __shfl_xor(ss, 32);
      if (lane < 16) {
        part2[(size_t)blockIdx.x * 512 + col] = s;
        part2[(size_t)blockIdx.x * 512 + 256 + col] = ss;
      }
    }
  } else {
    int q0 = m0 >> 5;   // 2 queries per block (32 samples each)
#pragma unroll
    for (int nt = 0; nt < 4; ++nt) {
      int col = wn0 + nt * 16 + r15;
      float bv = b2[col];
      float a2 = bn2c[col], c2 = bn2c[256 + col];
      float mA = -3.0e38f, mB = -3.0e38f;
#pragma unroll
      for (int mt = 0; mt < 4; ++mt)
#pragma unroll
        for (int rg = 0; rg < 4; ++rg) {
          float v = a2 * (acc[mt][nt][rg] + bv) + c2;
          if (mt < 2) mA = fmaxf(mA, v); else mB = fmaxf(mB, v);
        }
      mA = fmaxf(mA, __shfl_xor(mA, 16)); mA = fmaxf(mA, __shfl_xor(mA, 32));
      mB = fmaxf(mB, __shfl_xor(mB, 16)); mB = fmaxf(mB, __shfl_xor(mB, 32));
      if (lane < 32) {
        int q = q0 + (lane >> 4);
        float m = (lane < 16) ? mA : mB;
        int b = q >> 10, sIdx = q & (Sn - 1);
        out[OUT_XYZ + ((size_t)(b * C2 + col)) * Sn + sIdx] = fmaxf(0.f, m);
      }
    }
  }
}

// ---------- stats reduce (layer2) ----------
__global__ __launch_bounds__(512) void k_red2a(const float* __restrict__ part2,
                                               float* __restrict__ p2b) {
  int t = threadIdx.x, r = blockIdx.x;       // 128 blocks x 32 rows
  float acc = 0.f;
  for (int row = r * 32; row < r * 32 + 32; ++row)
    acc += part2[(size_t)row * 512 + t];
  p2b[r * 512 + t] = acc;
}
__global__ __launch_bounds__(512) void k_red2b(const float* __restrict__ p2b,
                                               const float* __restrict__ g2,
                                               const float* __restrict__ be2,
                                               float* __restrict__ bn2) {
  __shared__ float lds[512];
  int t = threadIdx.x;
  float acc = 0.f;
  for (int row = 0; row < 128; ++row) acc += p2b[row * 512 + t];
  lds[t] = acc;
  __syncthreads();
  if (t < 256) {
    float sum = lds[t], ss = lds[256 + t];
    float mean = sum / (float)Mm;
    float var = ss / (float)Mm - mean * mean;
    float a = g2[t] * rsqrtf(var + BNEPS);
    bn2[t] = a;
    bn2[256 + t] = be2[t] - mean * a;
  }
}

extern "C" void kernel_launch(void* const* d_in, const int* in_sizes, int n_in,
                              void* d_out, int out_size, void* d_ws, size_t ws_size,
                              hipStream_t stream) {
  (void)in_sizes; (void)n_in; (void)out_size; (void)ws_size;
  const float* xyz  = (const float*)d_in[0];
  const float* pts  = (const float*)d_in[1];
  const float* nxyz = (const float*)d_in[2];
  const float* W1   = (const float*)d_in[3];
  const float* b1   = (const float*)d_in[4];
  const float* g1   = (const float*)d_in[5];
  const float* be1  = (const float*)d_in[6];
  const float* W2   = (const float*)d_in[7];
  const float* b2   = (const float*)d_in[8];
  const float* g2   = (const float*)d_in[9];
  const float* be2  = (const float*)d_in[10];
  float* out = (float*)d_out;
  char* ws = (char*)d_ws;

  int*            idx   = (int*)(ws + OFF_IDX);
  float*          ptsT  = (float*)(ws + OFF_PTST);
  float*          part1 = (float*)(ws + OFF_P1);
  float*          part2 = (float*)(ws + OFF_P2);
  float*          p1b   = (float*)(ws + OFF_P1B);
  float*          p2b   = (float*)(ws + OFF_P2B);
  float*          bn1   = (float*)(ws + OFF_BN1);
  float*          bn2   = (float*)(ws + OFF_BN2);
  unsigned short* w2f   = (unsigned short*)(ws + OFF_W2F);
  unsigned short* y1    = (unsigned short*)(ws + OFF_Y1);

  k_copy_nxyz<<<(OUT_XYZ + 255) / 256, 256, 0, stream>>>(nxyz, out);
  k_ptsT<<<dim3(Nn / 64, Bn), 256, 0, stream>>>(pts, ptsT);
  k_w2f<<<128, 256, 0, stream>>>(W2, w2f);
  k_knn<<<Qq, 256, 0, stream>>>(xyz, nxyz, idx);
  k_mlp1<<<NB_MLP, 256, 0, stream>>>(W1, b1, ptsT, xyz, nxyz, idx, y1, part1);
  k_red1a<<<128, 256, 0, stream>>>(part1, p1b);
  k_red1b<<<1, 256, 0, stream>>>(p1b, g1, be1, bn1);
  k_m2<0><<<NB_MLP, 256, 0, stream>>>(y1, bn1, w2f, b2, part2, bn2, out);
  k_red2a<<<128, 512, 0, stream>>>(part2, p2b);
  k_red2b<<<1, 512, 0, stream>>>(p2b, g2, be2, bn2);
  k_m2<1><<<NB_MLP, 256, 0, stream>>>(y1, bn1, w2f, b2, part2, bn2, out);
}

// Round 4
// 374.050 us; speedup vs baseline: 2.3453x; 1.3665x over previous
//
#include <hip/hip_runtime.h>
#include <stdint.h>

constexpr int Bn = 8, Nn = 4096, Sn = 1024, Cc = 64, KNN = 32, C1 = 128, C2 = 256;
constexpr int Qq = Bn * Sn;     // 8192 queries
constexpr int Mm = Qq * KNN;    // 262144 samples
constexpr int OUT_XYZ = Bn * Sn * 3;  // 24576 floats (output 0)
constexpr float BNEPS = 1e-5f;

// ---------- ws layout ----------
constexpr size_t SZ_IDX  = (size_t)Qq * KNN * 4;        // 1 MB
constexpr size_t SZ_PTST = (size_t)Bn * Nn * Cc * 4;    // 8 MB
constexpr int    NB_MLP  = Mm / 64;                     // 4096 blocks
constexpr size_t SZ_PART = (size_t)NB_MLP * 512 * 4;    // 8 MB
constexpr size_t SZ_PB   = (size_t)128 * 512 * 4;       // 256 KB
constexpr size_t OFF_IDX  = 0;
constexpr size_t OFF_PTST = OFF_IDX + SZ_IDX;
constexpr size_t OFF_P1   = OFF_PTST + SZ_PTST;
constexpr size_t OFF_P2   = OFF_P1 + SZ_PART;
constexpr size_t OFF_P1B  = OFF_P2 + SZ_PART;
constexpr size_t OFF_P2B  = OFF_P1B + SZ_PB;
constexpr size_t OFF_BN1  = OFF_P2B + SZ_PB;
constexpr size_t OFF_BN2  = OFF_BN1 + 1024;
constexpr size_t OFF_W2F  = OFF_BN2 + 2048;              // 64 KB bf16 frag-packed W2
constexpr size_t OFF_Y1   = (OFF_W2F + (size_t)C1 * C2 * 2 + 255) & ~(size_t)255;
// total ws need ≈ OFF_Y1 + 67 MB

typedef __attribute__((ext_vector_type(8))) __bf16 bf16x8;
typedef __attribute__((ext_vector_type(4))) float f32x4;

__device__ __forceinline__ unsigned short f2bf(float f) {
  unsigned u = __float_as_uint(f);
  u = u + 0x7FFFu + ((u >> 16) & 1u);   // RNE
  return (unsigned short)(u >> 16);
}

// ---------- trivial copy of new_xyz to output 0 ----------
__global__ __launch_bounds__(256) void k_copy_nxyz(const float* __restrict__ src,
                                                   float* __restrict__ dst) {
  int i = threadIdx.x + blockIdx.x * 256;
  if (i < OUT_XYZ) dst[i] = src[i];
}

// ---------- points [B,C,N] -> ptsT [B,N,C] ----------
__global__ __launch_bounds__(256) void k_ptsT(const float* __restrict__ pts,
                                              float* __restrict__ ptsT) {
  __shared__ float tile[64][65];
  int b = blockIdx.y, n0 = blockIdx.x * 64;
  int cl = threadIdx.x & 63, rw = threadIdx.x >> 6;
#pragma unroll
  for (int i = 0; i < 16; ++i) {
    int c = i * 4 + rw;
    tile[cl][c] = pts[((size_t)b * Cc + c) * Nn + n0 + cl];
  }
  __syncthreads();
#pragma unroll
  for (int i = 0; i < 16; ++i) {
    int nf = i * 4 + rw;
    ptsT[((size_t)b * Nn + n0 + nf) * Cc + cl] = tile[nf][cl];
  }
}

// ---------- W2 [256,128] f32 -> bf16 MFMA B-fragment order ----------
__global__ __launch_bounds__(256) void k_w2f(const float* __restrict__ W2,
                                             unsigned short* __restrict__ w2f) {
  int u = threadIdx.x + blockIdx.x * 256;   // 32768 total
  int j = u & 7, lane = (u >> 3) & 63, ks = (u >> 9) & 3, ntile = u >> 11;
  int col = ntile * 16 + (lane & 15);
  int k = ks * 32 + (lane >> 4) * 8 + j;
  w2f[u] = f2bf(W2[col * C1 + k]);
}

// ---------- kNN via 4-pass radix select (exact top_k set + tie semantics) ----------
// Distance bits replicate the reference evaluation:
//   norms: mul then sequential adds (no FMA); dot: FMA chain; (A+B) - 2*dot.
// Selection: set of K smallest distances; ties broken by smallest point index.
// Output order within the K slots is arbitrary (downstream is order-invariant).
__global__ __launch_bounds__(256) void k_knn(const float* __restrict__ xyz,
                                             const float* __restrict__ nxyz,
                                             int* __restrict__ idxout) {
  int q = blockIdx.x, b = q >> 10, t = threadIdx.x;
  int lane = t & 63, w = t >> 6;
  const float* xb = xyz + (size_t)b * Nn * 3;
  float qx = nxyz[q * 3 + 0], qy = nxyz[q * 3 + 1], qz = nxyz[q * 3 + 2];
  float sqq = __fadd_rn(__fadd_rn(__fmul_rn(qx, qx), __fmul_rn(qy, qy)), __fmul_rn(qz, qz));
  unsigned key[16];
#pragma unroll
  for (int i = 0; i < 16; ++i) {
    int p = t + (i << 8);
    float xl = xb[p * 3 + 0], yl = xb[p * 3 + 1], zl = xb[p * 3 + 2];
    float sqp = __fadd_rn(__fadd_rn(__fmul_rn(xl, xl), __fmul_rn(yl, yl)), __fmul_rn(zl, zl));
    float dot = __fmaf_rn(qz, zl, __fmaf_rn(qy, yl, __fmul_rn(qx, xl)));
    float d = __fsub_rn(__fadd_rn(sqq, sqp), __fmul_rn(2.0f, dot));
    unsigned u = __float_as_uint(d);
    key[i] = (u & 0x80000000u) ? ~u : (u | 0x80000000u);   // monotone map
  }
  __shared__ unsigned hist[256];
  __shared__ unsigned wsum[4];
  __shared__ unsigned sel_bin, sel_off;
  unsigned prefix = 0, remaining = (unsigned)KNN;
#pragma unroll
  for (int shift = 24; shift >= 0; shift -= 8) {
    hist[t] = 0;
    __syncthreads();
    unsigned himask = (shift == 24) ? 0u : (0xFFFFFFFFu << ((shift + 8) & 31));
#pragma unroll
    for (int i = 0; i < 16; ++i)
      if ((key[i] & himask) == prefix)
        atomicAdd(&hist[(key[i] >> shift) & 255], 1u);
    __syncthreads();
    unsigned h = hist[t], v = h;
#pragma unroll
    for (int off = 1; off < 64; off <<= 1) {
      unsigned o = __shfl_up(v, off);
      if (lane >= off) v += o;
    }
    if (lane == 63) wsum[w] = v;
    __syncthreads();
    unsigned woff = 0;
    for (int ww = 0; ww < w; ++ww) woff += wsum[ww];
    v += woff;
    unsigned vex = v - h;
    if (vex < remaining && remaining <= v) { sel_bin = (unsigned)t; sel_off = vex; }
    __syncthreads();
    prefix |= sel_bin << shift;
    remaining -= sel_off;
  }
  // prefix = key of the K-th smallest; remaining = #(==prefix) to take by ascending index
  __shared__ unsigned cnt, eqcnt;
  __shared__ int eqbuf[128];
  if (t == 0) { cnt = 0; eqcnt = 0; }
  __syncthreads();
#pragma unroll
  for (int i = 0; i < 16; ++i) {
    int p = t + (i << 8);
    if (key[i] < prefix) {
      unsigned pos = atomicAdd(&cnt, 1u);
      idxout[q * KNN + pos] = p;
    } else if (key[i] == prefix) {
      unsigned e = atomicAdd(&eqcnt, 1u);
      if (e < 128u) eqbuf[e] = p;
    }
  }
  __syncthreads();
  if (t == 0) {
    int n = (int)min(eqcnt, 128u);
    for (int a = 1; a < n; ++a) {        // tiny insertion sort (usually n==1)
      int x = eqbuf[a], bi = a - 1;
      while (bi >= 0 && eqbuf[bi] > x) { eqbuf[bi + 1] = eqbuf[bi]; --bi; }
      eqbuf[bi + 1] = x;
    }
    int base = (int)cnt;
    for (int j = 0; j < (int)remaining; ++j) idxout[q * KNN + base + j] = eqbuf[j];
  }
}

// ---------- layer1: gather + W1 matvec + bias; write y1 bf16; stats partials ----------
__global__ __launch_bounds__(256) void k_mlp1(const float* __restrict__ W1g,
                                              const float* __restrict__ b1,
                                              const float* __restrict__ ptsT,
                                              const float* __restrict__ xyz,
                                              const float* __restrict__ nxyz,
                                              const int* __restrict__ idx,
                                              unsigned short* __restrict__ y1,
                                              float* __restrict__ part1) {
  __shared__ float w1s[C1 * 72];   // [128][72], cols 70..71 zero
  __shared__ float gs[64 * 72];    // [64 samples][72]
  int t = threadIdx.x;
  int m0 = blockIdx.x * 64;
  int b = m0 >> 15;                // S*K = 32768 samples per batch
  for (int u = t; u < C1 * 72; u += 256) {
    int ch = u / 72, c = u - ch * 72;
    w1s[u] = (c < 70) ? W1g[ch * 70 + c] : 0.0f;
  }
  {
    int j = t & 63, quarter = t >> 6;
    int m = m0 + j;
    int pid = idx[m];
    const float* src = ptsT + ((size_t)b * Nn + pid) * Cc + quarter * 16;
    float* dst = gs + j * 72 + quarter * 16;
#pragma unroll
    for (int u = 0; u < 16; u += 4)
      *reinterpret_cast<float4*>(dst + u) = *reinterpret_cast<const float4*>(src + u);
    if (quarter == 0) {
      int s = (m >> 5) & (Sn - 1);
      const float* xp = xyz + ((size_t)b * Nn + pid) * 3;
      gs[j * 72 + 64] = xp[0]; gs[j * 72 + 65] = xp[1]; gs[j * 72 + 66] = xp[2];
      const float* qp = nxyz + ((size_t)(b * Sn + s)) * 3;
      gs[j * 72 + 67] = qp[0]; gs[j * 72 + 68] = qp[1]; gs[j * 72 + 69] = qp[2];
      gs[j * 72 + 70] = 0.0f; gs[j * 72 + 71] = 0.0f;
    }
  }
  __syncthreads();
  int ch = t & 127, h = t >> 7;
  float acc[32];
  float bv = b1[ch];
#pragma unroll
  for (int j = 0; j < 32; ++j) acc[j] = bv;
  const float* gbase = gs + (h * 32) * 72;
  for (int c0 = 0; c0 < 72; c0 += 4) {
    float4 wv = *reinterpret_cast<const float4*>(w1s + ch * 72 + c0);
#pragma unroll
    for (int j = 0; j < 32; ++j) {
      float4 gv = *reinterpret_cast<const float4*>(gbase + j * 72 + c0);
      acc[j] += wv.x * gv.x + wv.y * gv.y + wv.z * gv.z + wv.w * gv.w;
    }
  }
  float sum = 0.f, ss = 0.f;
#pragma unroll
  for (int j = 0; j < 32; ++j) {
    float v = acc[j];
    sum += v; ss += v * v;
    y1[(size_t)(m0 + h * 32 + j) * C1 + ch] = f2bf(v);
  }
  float* p = part1 + (size_t)blockIdx.x * 512;
  p[h * 128 + ch] = sum;
  p[256 + h * 128 + ch] = ss;
}

// ---------- stats reduce (layer1) ----------
__global__ __launch_bounds__(256) void k_red1a(const float* __restrict__ part1,
                                               float* __restrict__ p1b) {
  int t = threadIdx.x, r = blockIdx.x;       // 128 blocks x 32 rows
  int ch = t & 127, which = t >> 7;
  float acc = 0.f;
  for (int row = r * 32; row < r * 32 + 32; ++row) {
    const float* p = part1 + (size_t)row * 512 + which * 256;
    acc += p[ch] + p[128 + ch];
  }
  p1b[r * 256 + which * 128 + ch] = acc;
}
__global__ __launch_bounds__(256) void k_red1b(const float* __restrict__ p1b,
                                               const float* __restrict__ g1,
                                               const float* __restrict__ be1,
                                               float* __restrict__ bn1) {
  __shared__ float lds[256];
  int t = threadIdx.x;
  float acc = 0.f;
  for (int row = 0; row < 128; ++row) acc += p1b[row * 256 + t];
  lds[t] = acc;
  __syncthreads();
  if (t < 128) {
    float sum = lds[t], ss = lds[128 + t];
    float mean = sum / (float)Mm;
    float var = ss / (float)Mm - mean * mean;
    float a = g1[t] * rsqrtf(var + BNEPS);
    bn1[t] = a;
    bn1[128 + t] = be1[t] - mean * a;
  }
}

// ---------- layer2 MFMA: z1=BNrelu(y1) bf16 -> y2 = W2 z1 + b2 (in acc) ----------
template <int OUTP>
__global__ __launch_bounds__(256) void k_m2(const unsigned short* __restrict__ y1,
                                            const float* __restrict__ bn1c,
                                            const unsigned short* __restrict__ w2f,
                                            const float* __restrict__ b2,
                                            float* __restrict__ part2,
                                            const float* __restrict__ bn2c,
                                            float* __restrict__ out) {
  __shared__ unsigned short zs[64 * 128];   // XOR-swizzled, byte ^= (row&7)<<4
  __shared__ float bns[256];
  int t = threadIdx.x;
  int m0 = blockIdx.x * 64;
  bns[t] = bn1c[t];
  uint4 yv[4];
  const uint4* ybase = reinterpret_cast<const uint4*>(y1 + (size_t)m0 * C1);
#pragma unroll
  for (int i = 0; i < 4; ++i) yv[i] = ybase[t + i * 256];
  int lane = t & 63, w = t >> 6;
  bf16x8 bfrag[4][4];
  {
    const uint4* wp = reinterpret_cast<const uint4*>(w2f) + (size_t)(w * 4) * 4 * 64 + lane;
#pragma unroll
    for (int nt = 0; nt < 4; ++nt)
#pragma unroll
      for (int ks = 0; ks < 4; ++ks)
        bfrag[nt][ks] = __builtin_bit_cast(bf16x8, wp[(nt * 4 + ks) * 64]);
  }
  __syncthreads();   // bns ready
#pragma unroll
  for (int i = 0; i < 4; ++i) {
    int chunk = t + i * 256;
    int row = chunk >> 4, kc = chunk & 15;
    unsigned arr[4] = {yv[i].x, yv[i].y, yv[i].z, yv[i].w};
    unsigned zo[4];
#pragma unroll
    for (int e = 0; e < 4; ++e) {
      int c = kc * 8 + e * 2;
      float lo = __uint_as_float(arr[e] << 16);
      float hi = __uint_as_float(arr[e] & 0xFFFF0000u);
      float z0 = fmaxf(0.f, bns[c] * lo + bns[128 + c]);
      float z1 = fmaxf(0.f, bns[c + 1] * hi + bns[128 + c + 1]);
      zo[e] = (unsigned)f2bf(z0) | ((unsigned)f2bf(z1) << 16);
    }
    int byte = (row * 256 + kc * 16) ^ ((row & 7) << 4);
    *reinterpret_cast<uint4*>(reinterpret_cast<char*>(zs) + byte) =
        make_uint4(zo[0], zo[1], zo[2], zo[3]);
  }
  __syncthreads();
  f32x4 acc[4][4];
#pragma unroll
  for (int mt = 0; mt < 4; ++mt)
#pragma unroll
    for (int nt = 0; nt < 4; ++nt) acc[mt][nt] = f32x4{0.f, 0.f, 0.f, 0.f};
  int r15 = lane & 15, rhi = lane >> 4;
#pragma unroll
  for (int mt = 0; mt < 4; ++mt) {
    int row = mt * 16 + r15;
    bf16x8 af[4];
#pragma unroll
    for (int ks = 0; ks < 4; ++ks) {
      int byte = (row * 256 + ks * 64 + rhi * 16) ^ ((row & 7) << 4);
      af[ks] = __builtin_bit_cast(
          bf16x8, *reinterpret_cast<const uint4*>(reinterpret_cast<const char*>(zs) + byte));
    }
#pragma unroll
    for (int nt = 0; nt < 4; ++nt)
#pragma unroll
      for (int ks = 0; ks < 4; ++ks)
        acc[mt][nt] =
            __builtin_amdgcn_mfma_f32_16x16x32_bf16(af[ks], bfrag[nt][ks], acc[mt][nt], 0, 0, 0);
  }
  int wn0 = w * 64;
  if (OUTP == 0) {
#pragma unroll
    for (int nt = 0; nt < 4; ++nt) {
      int col = wn0 + nt * 16 + r15;
      float bv = b2[col];
      float s = 0.f, ss = 0.f;
#pragma unroll
      for (int mt = 0; mt < 4; ++mt)
#pragma unroll
        for (int rg = 0; rg < 4; ++rg) {
          float v = acc[mt][nt][rg] + bv;
          s += v; ss += v * v;
        }
      s += __shfl_xor(s, 16); s += __shfl_xor(s, 32);
      ss += __shfl_xor(ss, 16); ss += __shfl_xor(ss, 32);
      if (lane < 16) {
        part2[(size_t)blockIdx.x * 512 + col] = s;
        part2[(size_t)blockIdx.x * 512 + 256 + col] = ss;
      }
    }
  } else {
    int q0 = m0 >> 5;   // 2 queries per block (32 samples each)
#pragma unroll
    for (int nt = 0; nt < 4; ++nt) {
      int col = wn0 + nt * 16 + r15;
      float bv = b2[col];
      float a2 = bn2c[col], c2 = bn2c[256 + col];
      float mA = -3.0e38f, mB = -3.0e38f;
#pragma unroll
      for (int mt = 0; mt < 4; ++mt)
#pragma unroll
        for (int rg = 0; rg < 4; ++rg) {
          float v = a2 * (acc[mt][nt][rg] + bv) + c2;
          if (mt < 2) mA = fmaxf(mA, v); else mB = fmaxf(mB, v);
        }
      mA = fmaxf(mA, __shfl_xor(mA, 16)); mA = fmaxf(mA, __shfl_xor(mA, 32));
      mB = fmaxf(mB, __shfl_xor(mB, 16)); mB = fmaxf(mB, __shfl_xor(mB, 32));
      if (lane < 32) {
        int q = q0 + (lane >> 4);
        float m = (lane < 16) ? mA : mB;
        int b = q >> 10, sIdx = q & (Sn - 1);
        out[OUT_XYZ + ((size_t)(b * C2 + col)) * Sn + sIdx] = fmaxf(0.f, m);
      }
    }
  }
}

// ---------- stats reduce (layer2) ----------
__global__ __launch_bounds__(512) void k_red2a(const float* __restrict__ part2,
                                               float* __restrict__ p2b) {
  int t = threadIdx.x, r = blockIdx.x;       // 128 blocks x 32 rows
  float acc = 0.f;
  for (int row = r * 32; row < r * 32 + 32; ++row)
    acc += part2[(size_t)row * 512 + t];
  p2b[r * 512 + t] = acc;
}
__global__ __launch_bounds__(512) void k_red2b(const float* __restrict__ p2b,
                                               const float* __restrict__ g2,
                                               const float* __restrict__ be2,
                                               float* __restrict__ bn2) {
  __shared__ float lds[512];
  int t = threadIdx.x;
  float acc = 0.f;
  for (int row = 0; row < 128; ++row) acc += p2b[row * 512 + t];
  lds[t] = acc;
  __syncthreads();
  if (t < 256) {
    float sum = lds[t], ss = lds[256 + t];
    float mean = sum / (float)Mm;
    float var = ss / (float)Mm - mean * mean;
    float a = g2[t] * rsqrtf(var + BNEPS);
    bn2[t] = a;
    bn2[256 + t] = be2[t] - mean * a;
  }
}

extern "C" void kernel_launch(void* const* d_in, const int* in_sizes, int n_in,
                              void* d_out, int out_size, void* d_ws, size_t ws_size,
                              hipStream_t stream) {
  (void)in_sizes; (void)n_in; (void)out_size; (void)ws_size;
  const float* xyz  = (const float*)d_in[0];
  const float* pts  = (const float*)d_in[1];
  const float* nxyz = (const float*)d_in[2];
  const float* W1   = (const float*)d_in[3];
  const float* b1   = (const float*)d_in[4];
  const float* g1   = (const float*)d_in[5];
  const float* be1  = (const float*)d_in[6];
  const float* W2   = (const float*)d_in[7];
  const float* b2   = (const float*)d_in[8];
  const float* g2   = (const float*)d_in[9];
  const float* be2  = (const float*)d_in[10];
  float* out = (float*)d_out;
  char* ws = (char*)d_ws;

  int*            idx   = (int*)(ws + OFF_IDX);
  float*          ptsT  = (float*)(ws + OFF_PTST);
  float*          part1 = (float*)(ws + OFF_P1);
  float*          part2 = (float*)(ws + OFF_P2);
  float*          p1b   = (float*)(ws + OFF_P1B);
  float*          p2b   = (float*)(ws + OFF_P2B);
  float*          bn1   = (float*)(ws + OFF_BN1);
  float*          bn2   = (float*)(ws + OFF_BN2);
  unsigned short* w2f   = (unsigned short*)(ws + OFF_W2F);
  unsigned short* y1    = (unsigned short*)(ws + OFF_Y1);

  k_copy_nxyz<<<(OUT_XYZ + 255) / 256, 256, 0, stream>>>(nxyz, out);
  k_ptsT<<<dim3(Nn / 64, Bn), 256, 0, stream>>>(pts, ptsT);
  k_w2f<<<128, 256, 0, stream>>>(W2, w2f);
  k_knn<<<Qq, 256, 0, stream>>>(xyz, nxyz, idx);
  k_mlp1<<<NB_MLP, 256, 0, stream>>>(W1, b1, ptsT, xyz, nxyz, idx, y1, part1);
  k_red1a<<<128, 256, 0, stream>>>(part1, p1b);
  k_red1b<<<1, 256, 0, stream>>>(p1b, g1, be1, bn1);
  k_m2<0><<<NB_MLP, 256, 0, stream>>>(y1, bn1, w2f, b2, part2, bn2, out);
  k_red2a<<<128, 512, 0, stream>>>(part2, p2b);
  k_red2b<<<1, 512, 0, stream>>>(p2b, g2, be2, bn2);
  k_m2<1><<<NB_MLP, 256, 0, stream>>>(y1, bn1, w2f, b2, part2, bn2, out);
}

// Round 5
// 230.124 us; speedup vs baseline: 3.8121x; 1.6254x over previous
//
#include <hip/hip_runtime.h>
#include <stdint.h>

constexpr int Bn = 8, Nn = 4096, Sn = 1024, Cc = 64, KNN = 32, C1 = 128, C2 = 256;
constexpr int Qq = Bn * Sn;     // 8192 queries
constexpr int Mm = Qq * KNN;    // 262144 samples
constexpr int OUT_XYZ = Bn * Sn * 3;  // 24576 floats (output 0)
constexpr float BNEPS = 1e-5f;

// ---------- ws layout ----------
constexpr size_t SZ_IDX  = (size_t)Qq * KNN * 4;        // 1 MB
constexpr size_t SZ_PTST = (size_t)Bn * Nn * Cc * 2;    // 4 MB (bf16)
constexpr int    NB_MLP  = Mm / 64;                     // 4096 blocks
constexpr size_t SZ_P1   = (size_t)NB_MLP * 256 * 4;    // 4 MB
constexpr size_t SZ_P2   = (size_t)NB_MLP * 512 * 4;    // 8 MB
constexpr size_t OFF_IDX  = 0;
constexpr size_t OFF_PTST = OFF_IDX + SZ_IDX;
constexpr size_t OFF_P1   = OFF_PTST + SZ_PTST;
constexpr size_t OFF_P2   = OFF_P1 + SZ_P1;
constexpr size_t OFF_P1B  = OFF_P2 + SZ_P2;
constexpr size_t OFF_P2B  = OFF_P1B + (size_t)128 * 256 * 4;
constexpr size_t OFF_BN1  = OFF_P2B + (size_t)128 * 512 * 4;
constexpr size_t OFF_BN2  = OFF_BN1 + 1024;
constexpr size_t OFF_W2F  = OFF_BN2 + 2048;                  // 64 KB
constexpr size_t OFF_W1F  = OFF_W2F + (size_t)32768 * 2;     // 24 KB
constexpr size_t OFF_Y1   = (OFF_W1F + (size_t)12288 * 2 + 255) & ~(size_t)255;
// total ws need ≈ OFF_Y1 + 67 MB

typedef __attribute__((ext_vector_type(8))) __bf16 bf16x8;
typedef __attribute__((ext_vector_type(4))) float f32x4;

__device__ __forceinline__ unsigned short f2bf(float f) {
  unsigned u = __float_as_uint(f);
  u = u + 0x7FFFu + ((u >> 16) & 1u);   // RNE
  return (unsigned short)(u >> 16);
}

// ---------- trivial copy of new_xyz to output 0 ----------
__global__ __launch_bounds__(256) void k_copy_nxyz(const float* __restrict__ src,
                                                   float* __restrict__ dst) {
  int i = threadIdx.x + blockIdx.x * 256;
  if (i < OUT_XYZ) dst[i] = src[i];
}

// ---------- points [B,C,N] f32 -> ptsTbf [B,N,C] bf16 ----------
__global__ __launch_bounds__(256) void k_ptsTbf(const float* __restrict__ pts,
                                                unsigned short* __restrict__ ptsTbf) {
  __shared__ float tile[64][65];
  int b = blockIdx.y, n0 = blockIdx.x * 64;
  int cl = threadIdx.x & 63, rw = threadIdx.x >> 6;
#pragma unroll
  for (int i = 0; i < 16; ++i) {
    int c = i * 4 + rw;
    tile[cl][c] = pts[((size_t)b * Cc + c) * Nn + n0 + cl];
  }
  __syncthreads();
#pragma unroll
  for (int i = 0; i < 16; ++i) {
    int nf = i * 4 + rw;
    ptsTbf[((size_t)b * Nn + n0 + nf) * Cc + cl] = f2bf(tile[nf][cl]);
  }
}

// ---------- W1 [128,70] f32 -> bf16 B-fragments, K padded to 96 ----------
// w1f[((nt*3+ks)*64+lane)*8+j] = W1[nt*16+(lane&15)][ks*32+(lane>>4)*8+j], 0 for k>=70
__global__ __launch_bounds__(256) void k_w1f(const float* __restrict__ W1,
                                             unsigned short* __restrict__ w1f) {
  int u = threadIdx.x + blockIdx.x * 256;   // 12288 total
  int j = u & 7, lane = (u >> 3) & 63, rest = u >> 9;
  int ks = rest % 3, nt = rest / 3;
  int ch = nt * 16 + (lane & 15);
  int k = ks * 32 + (lane >> 4) * 8 + j;
  w1f[u] = (k < 70) ? f2bf(W1[ch * 70 + k]) : (unsigned short)0;
}

// ---------- W2 [256,128] f32 -> bf16 MFMA B-fragment order ----------
__global__ __launch_bounds__(256) void k_w2f(const float* __restrict__ W2,
                                             unsigned short* __restrict__ w2f) {
  int u = threadIdx.x + blockIdx.x * 256;   // 32768 total
  int j = u & 7, lane = (u >> 3) & 63, ks = (u >> 9) & 3, ntile = u >> 11;
  int col = ntile * 16 + (lane & 15);
  int k = ks * 32 + (lane >> 4) * 8 + j;
  w2f[u] = f2bf(W2[col * C1 + k]);
}

// ---------- kNN via 4-pass radix select (exact top_k set + tie semantics) ----------
__global__ __launch_bounds__(256) void k_knn(const float* __restrict__ xyz,
                                             const float* __restrict__ nxyz,
                                             int* __restrict__ idxout) {
  int q = blockIdx.x, b = q >> 10, t = threadIdx.x;
  int lane = t & 63, w = t >> 6;
  const float* xb = xyz + (size_t)b * Nn * 3;
  float qx = nxyz[q * 3 + 0], qy = nxyz[q * 3 + 1], qz = nxyz[q * 3 + 2];
  float sqq = __fadd_rn(__fadd_rn(__fmul_rn(qx, qx), __fmul_rn(qy, qy)), __fmul_rn(qz, qz));
  unsigned key[16];
#pragma unroll
  for (int i = 0; i < 16; ++i) {
    int p = t + (i << 8);
    float xl = xb[p * 3 + 0], yl = xb[p * 3 + 1], zl = xb[p * 3 + 2];
    float sqp = __fadd_rn(__fadd_rn(__fmul_rn(xl, xl), __fmul_rn(yl, yl)), __fmul_rn(zl, zl));
    float dot = __fmaf_rn(qz, zl, __fmaf_rn(qy, yl, __fmul_rn(qx, xl)));
    float d = __fsub_rn(__fadd_rn(sqq, sqp), __fmul_rn(2.0f, dot));
    unsigned u = __float_as_uint(d);
    key[i] = (u & 0x80000000u) ? ~u : (u | 0x80000000u);   // monotone map
  }
  __shared__ unsigned hist[256];
  __shared__ unsigned wsum[4];
  __shared__ unsigned sel_bin, sel_off;
  unsigned prefix = 0, remaining = (unsigned)KNN;
#pragma unroll
  for (int shift = 24; shift >= 0; shift -= 8) {
    hist[t] = 0;
    __syncthreads();
    unsigned himask = (shift == 24) ? 0u : (0xFFFFFFFFu << ((shift + 8) & 31));
#pragma unroll
    for (int i = 0; i < 16; ++i)
      if ((key[i] & himask) == prefix)
        atomicAdd(&hist[(key[i] >> shift) & 255], 1u);
    __syncthreads();
    unsigned h = hist[t], v = h;
#pragma unroll
    for (int off = 1; off < 64; off <<= 1) {
      unsigned o = __shfl_up(v, off);
      if (lane >= off) v += o;
    }
    if (lane == 63) wsum[w] = v;
    __syncthreads();
    unsigned woff = 0;
    for (int ww = 0; ww < w; ++ww) woff += wsum[ww];
    v += woff;
    unsigned vex = v - h;
    if (vex < remaining && remaining <= v) { sel_bin = (unsigned)t; sel_off = vex; }
    __syncthreads();
    prefix |= sel_bin << shift;
    remaining -= sel_off;
  }
  __shared__ unsigned cnt, eqcnt;
  __shared__ int eqbuf[128];
  if (t == 0) { cnt = 0; eqcnt = 0; }
  __syncthreads();
#pragma unroll
  for (int i = 0; i < 16; ++i) {
    int p = t + (i << 8);
    if (key[i] < prefix) {
      unsigned pos = atomicAdd(&cnt, 1u);
      idxout[q * KNN + pos] = p;
    } else if (key[i] == prefix) {
      unsigned e = atomicAdd(&eqcnt, 1u);
      if (e < 128u) eqbuf[e] = p;
    }
  }
  __syncthreads();
  if (t == 0) {
    int n = (int)min(eqcnt, 128u);
    for (int a = 1; a < n; ++a) {
      int x = eqbuf[a], bi = a - 1;
      while (bi >= 0 && eqbuf[bi] > x) { eqbuf[bi + 1] = eqbuf[bi]; --bi; }
      eqbuf[bi + 1] = x;
    }
    int base = (int)cnt;
    for (int j = 0; j < (int)remaining; ++j) idxout[q * KNN + base + j] = eqbuf[j];
  }
}

// ---------- layer1 MFMA: gather bf16 -> y1 = W1 g + b1; stats partials; y1 bf16 ----------
__global__ __launch_bounds__(256) void k_mlp1(const unsigned short* __restrict__ ptsTbf,
                                              const float* __restrict__ xyz,
                                              const float* __restrict__ nxyz,
                                              const int* __restrict__ idx,
                                              const unsigned short* __restrict__ w1f,
                                              const float* __restrict__ b1,
                                              unsigned short* __restrict__ y1,
                                              float* __restrict__ part1) {
  __shared__ unsigned short zs[64 * 128];   // A-tile (swz ^(row&7)<<4), then y1-T (swz ^(row&3)<<6)
  int t = threadIdx.x;
  int m0 = blockIdx.x * 64;
  int b = m0 >> 15;
  int lane = t & 63, w = t >> 6;
  // B fragments: this wave's 32 output channels (2 n-tiles x 3 k-steps)
  bf16x8 bfrag[2][3];
  {
    const uint4* wp = reinterpret_cast<const uint4*>(w1f);
#pragma unroll
    for (int nt = 0; nt < 2; ++nt)
#pragma unroll
      for (int ks = 0; ks < 3; ++ks)
        bfrag[nt][ks] = __builtin_bit_cast(bf16x8, wp[((w * 2 + nt) * 3 + ks) * 64 + lane]);
  }
  // A staging: 64 samples x 96 cols (70 real + zero pad), XOR-swizzled
  {
    int j = t >> 2, part = t & 3;
    int m = m0 + j;
    int pid = idx[m];
    const uint4* src =
        reinterpret_cast<const uint4*>(ptsTbf + ((size_t)b * Nn + pid) * Cc + part * 16);
    char* zc = reinterpret_cast<char*>(zs);
    int base = j * 256, swz = (j & 7) << 4;
    uint4 s0 = src[0], s1 = src[1];
    *reinterpret_cast<uint4*>(zc + ((base + part * 32) ^ swz)) = s0;
    *reinterpret_cast<uint4*>(zc + ((base + part * 32 + 16) ^ swz)) = s1;
    uint4 ex = make_uint4(0u, 0u, 0u, 0u);
    if (part == 0) {
      const float* xp = xyz + ((size_t)b * Nn + pid) * 3;
      int s = (m >> 5) & (Sn - 1);
      const float* qp = nxyz + (size_t)(b * Sn + s) * 3;
      ex.x = (unsigned)f2bf(xp[0]) | ((unsigned)f2bf(xp[1]) << 16);
      ex.y = (unsigned)f2bf(xp[2]) | ((unsigned)f2bf(qp[0]) << 16);
      ex.z = (unsigned)f2bf(qp[1]) | ((unsigned)f2bf(qp[2]) << 16);
    }
    *reinterpret_cast<uint4*>(zc + ((base + (8 + part) * 16) ^ swz)) = ex;
  }
  __syncthreads();
  // MFMA: 64 rows x 32 cols per wave, K=96
  f32x4 acc[4][2];
#pragma unroll
  for (int mt = 0; mt < 4; ++mt)
#pragma unroll
    for (int nt = 0; nt < 2; ++nt) acc[mt][nt] = f32x4{0.f, 0.f, 0.f, 0.f};
  int r15 = lane & 15, rhi = lane >> 4;
  const char* zc = reinterpret_cast<const char*>(zs);
#pragma unroll
  for (int mt = 0; mt < 4; ++mt) {
    int row = mt * 16 + r15;
    bf16x8 af[3];
#pragma unroll
    for (int ks = 0; ks < 3; ++ks)
      af[ks] = __builtin_bit_cast(
          bf16x8, *reinterpret_cast<const uint4*>(
                      zc + ((row * 256 + ks * 64 + rhi * 16) ^ ((row & 7) << 4))));
#pragma unroll
    for (int nt = 0; nt < 2; ++nt)
#pragma unroll
      for (int ks = 0; ks < 3; ++ks)
        acc[mt][nt] =
            __builtin_amdgcn_mfma_f32_16x16x32_bf16(af[ks], bfrag[nt][ks], acc[mt][nt], 0, 0, 0);
  }
  __syncthreads();   // A-tile reads done; reuse zs for y1 transpose
  char* zcw = reinterpret_cast<char*>(zs);
#pragma unroll
  for (int nt = 0; nt < 2; ++nt) {
    int col = w * 32 + nt * 16 + r15;
    float bv = b1[col];
    float s = 0.f, ss = 0.f;
#pragma unroll
    for (int mt = 0; mt < 4; ++mt)
#pragma unroll
      for (int rg = 0; rg < 4; ++rg) {
        float v = acc[mt][nt][rg] + bv;
        s += v; ss += v * v;
        int row = mt * 16 + rhi * 4 + rg;
        *reinterpret_cast<unsigned short*>(zcw + ((row * 256 + col * 2) ^ ((row & 3) << 6))) =
            f2bf(v);
      }
    s += __shfl_xor(s, 16); s += __shfl_xor(s, 32);
    ss += __shfl_xor(ss, 16); ss += __shfl_xor(ss, 32);
    if (lane < 16) {
      part1[(size_t)blockIdx.x * 256 + col] = s;
      part1[(size_t)blockIdx.x * 256 + 128 + col] = ss;
    }
  }
  __syncthreads();
  // coalesced y1 store
#pragma unroll
  for (int i = 0; i < 4; ++i) {
    int chunk = t + i * 256;
    int row = chunk >> 4, kc = chunk & 15;
    uint4 v = *reinterpret_cast<const uint4*>(
        zc + ((row * 256 + kc * 16) ^ ((row & 3) << 6)));
    *reinterpret_cast<uint4*>(y1 + (size_t)(m0 + row) * C1 + kc * 8) = v;
  }
}

// ---------- stats reduce (layer1) ----------
__global__ __launch_bounds__(256) void k_red1a(const float* __restrict__ part1,
                                               float* __restrict__ p1b) {
  int t = threadIdx.x, r = blockIdx.x;       // 128 blocks x 32 rows
  float acc = 0.f;
  for (int row = r * 32; row < r * 32 + 32; ++row)
    acc += part1[(size_t)row * 256 + t];
  p1b[r * 256 + t] = acc;
}
__global__ __launch_bounds__(256) void k_red1b(const float* __restrict__ p1b,
                                               const float* __restrict__ g1,
                                               const float* __restrict__ be1,
                                               float* __restrict__ bn1) {
  __shared__ float lds[256];
  int t = threadIdx.x;
  float acc = 0.f;
  for (int row = 0; row < 128; ++row) acc += p1b[row * 256 + t];
  lds[t] = acc;
  __syncthreads();
  if (t < 128) {
    float sum = lds[t], ss = lds[128 + t];
    float mean = sum / (float)Mm;
    float var = ss / (float)Mm - mean * mean;
    float a = g1[t] * rsqrtf(var + BNEPS);
    bn1[t] = a;
    bn1[128 + t] = be1[t] - mean * a;
  }
}

// ---------- layer2 MFMA: z1=BNrelu(y1) bf16 -> y2 = W2 z1 + b2 (in acc) ----------
template <int OUTP>
__global__ __launch_bounds__(256) void k_m2(const unsigned short* __restrict__ y1,
                                            const float* __restrict__ bn1c,
                                            const unsigned short* __restrict__ w2f,
                                            const float* __restrict__ b2,
                                            float* __restrict__ part2,
                                            const float* __restrict__ bn2c,
                                            float* __restrict__ out) {
  __shared__ unsigned short zs[64 * 128];   // XOR-swizzled, byte ^= (row&7)<<4
  __shared__ float bns[256];
  int t = threadIdx.x;
  int m0 = blockIdx.x * 64;
  bns[t] = bn1c[t];
  uint4 yv[4];
  const uint4* ybase = reinterpret_cast<const uint4*>(y1 + (size_t)m0 * C1);
#pragma unroll
  for (int i = 0; i < 4; ++i) yv[i] = ybase[t + i * 256];
  int lane = t & 63, w = t >> 6;
  bf16x8 bfrag[4][4];
  {
    const uint4* wp = reinterpret_cast<const uint4*>(w2f) + (size_t)(w * 4) * 4 * 64 + lane;
#pragma unroll
    for (int nt = 0; nt < 4; ++nt)
#pragma unroll
      for (int ks = 0; ks < 4; ++ks)
        bfrag[nt][ks] = __builtin_bit_cast(bf16x8, wp[(nt * 4 + ks) * 64]);
  }
  __syncthreads();   // bns ready
#pragma unroll
  for (int i = 0; i < 4; ++i) {
    int chunk = t + i * 256;
    int row = chunk >> 4, kc = chunk & 15;
    unsigned arr[4] = {yv[i].x, yv[i].y, yv[i].z, yv[i].w};
    unsigned zo[4];
#pragma unroll
    for (int e = 0; e < 4; ++e) {
      int c = kc * 8 + e * 2;
      float lo = __uint_as_float(arr[e] << 16);
      float hi = __uint_as_float(arr[e] & 0xFFFF0000u);
      float z0 = fmaxf(0.f, bns[c] * lo + bns[128 + c]);
      float z1 = fmaxf(0.f, bns[c + 1] * hi + bns[128 + c + 1]);
      zo[e] = (unsigned)f2bf(z0) | ((unsigned)f2bf(z1) << 16);
    }
    int byte = (row * 256 + kc * 16) ^ ((row & 7) << 4);
    *reinterpret_cast<uint4*>(reinterpret_cast<char*>(zs) + byte) =
        make_uint4(zo[0], zo[1], zo[2], zo[3]);
  }
  __syncthreads();
  f32x4 acc[4][4];
#pragma unroll
  for (int mt = 0; mt < 4; ++mt)
#pragma unroll
    for (int nt = 0; nt < 4; ++nt) acc[mt][nt] = f32x4{0.f, 0.f, 0.f, 0.f};
  int r15 = lane & 15, rhi = lane >> 4;
#pragma unroll
  for (int mt = 0; mt < 4; ++mt) {
    int row = mt * 16 + r15;
    bf16x8 af[4];
#pragma unroll
    for (int ks = 0; ks < 4; ++ks) {
      int byte = (row * 256 + ks * 64 + rhi * 16) ^ ((row & 7) << 4);
      af[ks] = __builtin_bit_cast(
          bf16x8, *reinterpret_cast<const uint4*>(reinterpret_cast<const char*>(zs) + byte));
    }
#pragma unroll
    for (int nt = 0; nt < 4; ++nt)
#pragma unroll
      for (int ks = 0; ks < 4; ++ks)
        acc[mt][nt] =
            __builtin_amdgcn_mfma_f32_16x16x32_bf16(af[ks], bfrag[nt][ks], acc[mt][nt], 0, 0, 0);
  }
  int wn0 = w * 64;
  if (OUTP == 0) {
#pragma unroll
    for (int nt = 0; nt < 4; ++nt) {
      int col = wn0 + nt * 16 + r15;
      float bv = b2[col];
      float s = 0.f, ss = 0.f;
#pragma unroll
      for (int mt = 0; mt < 4; ++mt)
#pragma unroll
        for (int rg = 0; rg < 4; ++rg) {
          float v = acc[mt][nt][rg] + bv;
          s += v; ss += v * v;
        }
      s += __shfl_xor(s, 16); s += __shfl_xor(s, 32);
      ss += __shfl_xor(ss, 16); ss += __shfl_xor(ss, 32);
      if (lane < 16) {
        part2[(size_t)blockIdx.x * 512 + col] = s;
        part2[(size_t)blockIdx.x * 512 + 256 + col] = ss;
      }
    }
  } else {
    int q0 = m0 >> 5;   // 2 queries per block (32 samples each)
#pragma unroll
    for (int nt = 0; nt < 4; ++nt) {
      int col = wn0 + nt * 16 + r15;
      float bv = b2[col];
      float a2 = bn2c[col], c2 = bn2c[256 + col];
      float mA = -3.0e38f, mB = -3.0e38f;
#pragma unroll
      for (int mt = 0; mt < 4; ++mt)
#pragma unroll
        for (int rg = 0; rg < 4; ++rg) {
          float v = a2 * (acc[mt][nt][rg] + bv) + c2;
          if (mt < 2) mA = fmaxf(mA, v); else mB = fmaxf(mB, v);
        }
      mA = fmaxf(mA, __shfl_xor(mA, 16)); mA = fmaxf(mA, __shfl_xor(mA, 32));
      mB = fmaxf(mB, __shfl_xor(mB, 16)); mB = fmaxf(mB, __shfl_xor(mB, 32));
      if (lane < 32) {
        int q = q0 + (lane >> 4);
        float m = (lane < 16) ? mA : mB;
        int b = q >> 10, sIdx = q & (Sn - 1);
        out[OUT_XYZ + ((size_t)(b * C2 + col)) * Sn + sIdx] = fmaxf(0.f, m);
      }
    }
  }
}

// ---------- stats reduce (layer2) ----------
__global__ __launch_bounds__(512) void k_red2a(const float* __restrict__ part2,
                                               float* __restrict__ p2b) {
  int t = threadIdx.x, r = blockIdx.x;       // 128 blocks x 32 rows
  float acc = 0.f;
  for (int row = r * 32; row < r * 32 + 32; ++row)
    acc += part2[(size_t)row * 512 + t];
  p2b[r * 512 + t] = acc;
}
__global__ __launch_bounds__(512) void k_red2b(const float* __restrict__ p2b,
                                               const float* __restrict__ g2,
                                               const float* __restrict__ be2,
                                               float* __restrict__ bn2) {
  __shared__ float lds[512];
  int t = threadIdx.x;
  float acc = 0.f;
  for (int row = 0; row < 128; ++row) acc += p2b[row * 512 + t];
  lds[t] = acc;
  __syncthreads();
  if (t < 256) {
    float sum = lds[t], ss = lds[256 + t];
    float mean = sum / (float)Mm;
    float var = ss / (float)Mm - mean * mean;
    float a = g2[t] * rsqrtf(var + BNEPS);
    bn2[t] = a;
    bn2[256 + t] = be2[t] - mean * a;
  }
}

extern "C" void kernel_launch(void* const* d_in, const int* in_sizes, int n_in,
                              void* d_out, int out_size, void* d_ws, size_t ws_size,
                              hipStream_t stream) {
  (void)in_sizes; (void)n_in; (void)out_size; (void)ws_size;
  const float* xyz  = (const float*)d_in[0];
  const float* pts  = (const float*)d_in[1];
  const float* nxyz = (const float*)d_in[2];
  const float* W1   = (const float*)d_in[3];
  const float* b1   = (const float*)d_in[4];
  const float* g1   = (const float*)d_in[5];
  const float* be1  = (const float*)d_in[6];
  const float* W2   = (const float*)d_in[7];
  const float* b2   = (const float*)d_in[8];
  const float* g2   = (const float*)d_in[9];
  const float* be2  = (const float*)d_in[10];
  float* out = (float*)d_out;
  char* ws = (char*)d_ws;

  int*            idx    = (int*)(ws + OFF_IDX);
  unsigned short* ptsTbf = (unsigned short*)(ws + OFF_PTST);
  float*          part1  = (float*)(ws + OFF_P1);
  float*          part2  = (float*)(ws + OFF_P2);
  float*          p1b    = (float*)(ws + OFF_P1B);
  float*          p2b    = (float*)(ws + OFF_P2B);
  float*          bn1    = (float*)(ws + OFF_BN1);
  float*          bn2    = (float*)(ws + OFF_BN2);
  unsigned short* w2f    = (unsigned short*)(ws + OFF_W2F);
  unsigned short* w1f    = (unsigned short*)(ws + OFF_W1F);
  unsigned short* y1     = (unsigned short*)(ws + OFF_Y1);

  k_copy_nxyz<<<(OUT_XYZ + 255) / 256, 256, 0, stream>>>(nxyz, out);
  k_ptsTbf<<<dim3(Nn / 64, Bn), 256, 0, stream>>>(pts, ptsTbf);
  k_w1f<<<48, 256, 0, stream>>>(W1, w1f);
  k_w2f<<<128, 256, 0, stream>>>(W2, w2f);
  k_knn<<<Qq, 256, 0, stream>>>(xyz, nxyz, idx);
  k_mlp1<<<NB_MLP, 256, 0, stream>>>(ptsTbf, xyz, nxyz, idx, w1f, b1, y1, part1);
  k_red1a<<<128, 256, 0, stream>>>(part1, p1b);
  k_red1b<<<1, 256, 0, stream>>>(p1b, g1, be1, bn1);
  k_m2<0><<<NB_MLP, 256, 0, stream>>>(y1, bn1, w2f, b2, part2, bn2, out);
  k_red2a<<<128, 512, 0, stream>>>(part2, p2b);
  k_red2b<<<1, 512, 0, stream>>>(p2b, g2, be2, bn2);
  k_m2<1><<<NB_MLP, 256, 0, stream>>>(y1, bn1, w2f, b2, part2, bn2, out);
}